// Round 1
// baseline (10861.258 us; speedup 1.0000x reference)
//
#include <hip/hip_runtime.h>
#include <math.h>

// Problem constants
#define BATCH 4
#define SEQ   4096
#define HID   2048
#define HD    128
#define NROWS (BATCH*SEQ)          // 16384

static constexpr float OSCALE = 0.088388347648318447f;  // 1/sqrt(128), applied post-softmax

// ---------------------------------------------------------------------------
// QKV projection: out_m[r][d] = x[r][:] . W_m[:][d] + b_m[d]
// C tile 128x128 (blockIdx.y picks the matrix), BK=16, 256 threads, 8x8/thread
// ---------------------------------------------------------------------------
__global__ __launch_bounds__(256) void qkv_proj(
    const float* __restrict__ x,
    const float* __restrict__ Wq, const float* __restrict__ bq,
    const float* __restrict__ Wk, const float* __restrict__ bk,
    const float* __restrict__ Wv, const float* __restrict__ bv,
    float* __restrict__ qkv)
{
    __shared__ float As[16][132];   // [k][row], pad 4 keeps float4 alignment + banks spread
    __shared__ float Bs[16][132];   // [k][col]

    const int tid = threadIdx.x;
    const int r0  = blockIdx.x * 128;
    const int mm  = blockIdx.y;                    // 0=q 1=k 2=v
    const float* W    = (mm == 0) ? Wq : (mm == 1) ? Wk : Wv;
    const float* bias = (mm == 0) ? bq : (mm == 1) ? bk : bv;
    float* out = qkv + (size_t)mm * NROWS * HD;

    const int tm = tid >> 4;    // 0..15 -> rows tm*4 and 64+tm*4
    const int tn = tid & 15;    // 0..15 -> cols tn*4 and 64+tn*4

    float acc[8][8];
    #pragma unroll
    for (int i = 0; i < 8; ++i)
        #pragma unroll
        for (int j = 0; j < 8; ++j) acc[i][j] = 0.f;

    for (int k0 = 0; k0 < HID; k0 += 16) {
        float4 a[2], bw[2];
        #pragma unroll
        for (int i = 0; i < 2; ++i) {
            const int fi = i * 256 + tid;          // 0..511
            const int lr = fi >> 2;                // 0..127
            const int lc = (fi & 3) << 2;          // 0,4,8,12
            a[i] = *(const float4*)(x + (size_t)(r0 + lr) * HID + k0 + lc);
            const int br = fi >> 5;                // 0..15
            const int bn = (fi & 31) << 2;         // 0..124
            bw[i] = *(const float4*)(W + (size_t)(k0 + br) * HD + bn);
        }
        __syncthreads();   // previous tile's readers done
        #pragma unroll
        for (int i = 0; i < 2; ++i) {
            const int fi = i * 256 + tid;
            const int lr = fi >> 2;
            const int lc = (fi & 3) << 2;
            As[lc + 0][lr] = a[i].x;
            As[lc + 1][lr] = a[i].y;
            As[lc + 2][lr] = a[i].z;
            As[lc + 3][lr] = a[i].w;
            const int br = fi >> 5;
            const int bn = (fi & 31) << 2;
            *(float4*)&Bs[br][bn] = bw[i];
        }
        __syncthreads();
        #pragma unroll
        for (int kk = 0; kk < 16; ++kk) {
            float av[8], bv2[8];
            *(float4*)&av[0]  = *(const float4*)&As[kk][tm * 4];
            *(float4*)&av[4]  = *(const float4*)&As[kk][64 + tm * 4];
            *(float4*)&bv2[0] = *(const float4*)&Bs[kk][tn * 4];
            *(float4*)&bv2[4] = *(const float4*)&Bs[kk][64 + tn * 4];
            #pragma unroll
            for (int i = 0; i < 8; ++i)
                #pragma unroll
                for (int j = 0; j < 8; ++j)
                    acc[i][j] = fmaf(av[i], bv2[j], acc[i][j]);
        }
        __syncthreads();
    }

    #pragma unroll
    for (int i = 0; i < 8; ++i) {
        const int r = r0 + ((i < 4) ? (tm * 4 + i) : (64 + tm * 4 + (i - 4)));
        float* orow = out + (size_t)r * HD;
        const int c0 = tn * 4, c1 = 64 + tn * 4;
        float4 s0, s1;
        s0.x = acc[i][0] + bias[c0 + 0];
        s0.y = acc[i][1] + bias[c0 + 1];
        s0.z = acc[i][2] + bias[c0 + 2];
        s0.w = acc[i][3] + bias[c0 + 3];
        s1.x = acc[i][4] + bias[c1 + 0];
        s1.y = acc[i][5] + bias[c1 + 1];
        s1.z = acc[i][6] + bias[c1 + 2];
        s1.w = acc[i][7] + bias[c1 + 3];
        *(float4*)(orow + c0) = s0;
        *(float4*)(orow + c1) = s1;
    }
}

// ---------------------------------------------------------------------------
// Flash attention, fp32, causal, NO qk scaling, output scaled by 1/sqrt(D).
// BQ=32 q rows per tile, BK=64 kv rows per tile.
// 256 threads: rg = tid>>4 (owns rows rg, rg+16), cg = tid&15.
//   scores: thread computes 2 rows x 4 cols (cols cg+16*i)
//   PV:     thread computes 2 rows x 8 dims (dims cg*8..cg*8+7)
// One block handles q-tiles {pair, 127-pair} -> uniform work (129 kv32-steps).
// ---------------------------------------------------------------------------
__global__ __launch_bounds__(256) void flash_attn(
    const float* __restrict__ Qm, const float* __restrict__ Km,
    const float* __restrict__ Vm, float* __restrict__ Out)
{
    __shared__ float Qs[32][132];
    __shared__ float Ks[64][132];
    __shared__ float Vs[64][132];
    __shared__ float Ps[32][68];

    const int tid  = threadIdx.x;
    const int rg   = tid >> 4;      // 0..15
    const int cg   = tid & 15;      // 0..15
    const int b    = blockIdx.x >> 6;
    const int pair = blockIdx.x & 63;

    for (int half = 0; half < 2; ++half) {
        const int t = half ? (127 - pair) : pair;
        const size_t qrow0 = (size_t)b * SEQ + (size_t)t * 32;

        __syncthreads();   // previous half's LDS readers done
        #pragma unroll
        for (int i = 0; i < 4; ++i) {
            const int fi = i * 256 + tid;      // 0..1023
            const int lr = fi >> 5;            // 0..31
            const int lc = (fi & 31) << 2;     // 0..124
            *(float4*)&Qs[lr][lc] = *(const float4*)(Qm + (qrow0 + lr) * HD + lc);
        }
        __syncthreads();

        float o[2][8];
        #pragma unroll
        for (int rr = 0; rr < 2; ++rr)
            #pragma unroll
            for (int d = 0; d < 8; ++d) o[rr][d] = 0.f;
        float mrow[2] = { -INFINITY, -INFINITY };
        float lrow[2] = { 0.f, 0.f };

        const int jmax = t >> 1;   // kv tiles 0..jmax (64-wide)

        for (int j = 0; j <= jmax; ++j) {
            // ---- stage K,V tile (prior iteration's readers released by the
            //      trailing __syncthreads of the loop body / the Qs barrier) ----
            #pragma unroll
            for (int i = 0; i < 8; ++i) {
                const int fi = i * 256 + tid;  // 0..2047
                const int lr = fi >> 5;        // 0..63
                const int lc = (fi & 31) << 2;
                const size_t gb = ((size_t)b * SEQ + (size_t)j * 64 + lr) * HD + lc;
                *(float4*)&Ks[lr][lc] = *(const float4*)(Km + gb);
                *(float4*)&Vs[lr][lc] = *(const float4*)(Vm + gb);
            }
            __syncthreads();

            // ---- scores: 2 rows x 4 cols per thread ----
            float s[2][4];
            #pragma unroll
            for (int rr = 0; rr < 2; ++rr)
                #pragma unroll
                for (int i = 0; i < 4; ++i) s[rr][i] = 0.f;

            #pragma unroll 4
            for (int kk = 0; kk < 32; ++kk) {
                const float4 q0 = *(const float4*)&Qs[rg][kk << 2];
                const float4 q1 = *(const float4*)&Qs[rg + 16][kk << 2];
                #pragma unroll
                for (int i = 0; i < 4; ++i) {
                    const float4 kf = *(const float4*)&Ks[cg + 16 * i][kk << 2];
                    s[0][i] = fmaf(q0.x, kf.x, s[0][i]);
                    s[0][i] = fmaf(q0.y, kf.y, s[0][i]);
                    s[0][i] = fmaf(q0.z, kf.z, s[0][i]);
                    s[0][i] = fmaf(q0.w, kf.w, s[0][i]);
                    s[1][i] = fmaf(q1.x, kf.x, s[1][i]);
                    s[1][i] = fmaf(q1.y, kf.y, s[1][i]);
                    s[1][i] = fmaf(q1.z, kf.z, s[1][i]);
                    s[1][i] = fmaf(q1.w, kf.w, s[1][i]);
                }
            }

            if (j == jmax) {   // only the last tile can cross the diagonal
                #pragma unroll
                for (int rr = 0; rr < 2; ++rr) {
                    const int qidx = t * 32 + rg + 16 * rr;
                    #pragma unroll
                    for (int i = 0; i < 4; ++i) {
                        const int kidx = j * 64 + cg + 16 * i;
                        if (kidx > qidx) s[rr][i] = -INFINITY;
                    }
                }
            }

            // ---- online softmax (per row, reduce across the 16 cg lanes) ----
            #pragma unroll
            for (int rr = 0; rr < 2; ++rr) {
                float mt = fmaxf(fmaxf(s[rr][0], s[rr][1]), fmaxf(s[rr][2], s[rr][3]));
                mt = fmaxf(mt, __shfl_xor(mt, 1));
                mt = fmaxf(mt, __shfl_xor(mt, 2));
                mt = fmaxf(mt, __shfl_xor(mt, 4));
                mt = fmaxf(mt, __shfl_xor(mt, 8));
                const float mn    = fmaxf(mrow[rr], mt);
                const float alpha = __expf(mrow[rr] - mn);   // exp(-inf)=0 on first tile
                mrow[rr] = mn;
                float p[4], ps = 0.f;
                #pragma unroll
                for (int i = 0; i < 4; ++i) { p[i] = __expf(s[rr][i] - mn); ps += p[i]; }
                #pragma unroll
                for (int i = 0; i < 4; ++i) Ps[rg + 16 * rr][cg + 16 * i] = p[i];
                ps += __shfl_xor(ps, 1);
                ps += __shfl_xor(ps, 2);
                ps += __shfl_xor(ps, 4);
                ps += __shfl_xor(ps, 8);
                lrow[rr] = lrow[rr] * alpha + ps;
                #pragma unroll
                for (int d = 0; d < 8; ++d) o[rr][d] *= alpha;
            }
            __syncthreads();   // Ps visible to all

            // ---- PV: 2 rows x 8 dims per thread ----
            #pragma unroll 4
            for (int c = 0; c < 64; ++c) {
                const float p0 = Ps[rg][c];
                const float p1 = Ps[rg + 16][c];
                #pragma unroll
                for (int qi = 0; qi < 2; ++qi) {
                    const int qp = (qi + cg) & 1;               // bank-swizzled chunk order
                    const float4 vf = *(const float4*)&Vs[c][cg * 8 + qp * 4];
                    o[0][qp * 4 + 0] = fmaf(p0, vf.x, o[0][qp * 4 + 0]);
                    o[0][qp * 4 + 1] = fmaf(p0, vf.y, o[0][qp * 4 + 1]);
                    o[0][qp * 4 + 2] = fmaf(p0, vf.z, o[0][qp * 4 + 2]);
                    o[0][qp * 4 + 3] = fmaf(p0, vf.w, o[0][qp * 4 + 3]);
                    o[1][qp * 4 + 0] = fmaf(p1, vf.x, o[1][qp * 4 + 0]);
                    o[1][qp * 4 + 1] = fmaf(p1, vf.y, o[1][qp * 4 + 1]);
                    o[1][qp * 4 + 2] = fmaf(p1, vf.z, o[1][qp * 4 + 2]);
                    o[1][qp * 4 + 3] = fmaf(p1, vf.w, o[1][qp * 4 + 3]);
                }
            }
            __syncthreads();   // done with Ks/Vs/Ps for this tile
        }

        // ---- epilogue: out = (softmax @ V) * 1/sqrt(D) ----
        #pragma unroll
        for (int rr = 0; rr < 2; ++rr) {
            const float inv = OSCALE / lrow[rr];
            float* orow = Out + (qrow0 + rg + 16 * rr) * HD + cg * 8;
            float4 o0, o1;
            o0.x = o[rr][0] * inv; o0.y = o[rr][1] * inv;
            o0.z = o[rr][2] * inv; o0.w = o[rr][3] * inv;
            o1.x = o[rr][4] * inv; o1.y = o[rr][5] * inv;
            o1.z = o[rr][6] * inv; o1.w = o[rr][7] * inv;
            *(float4*)(orow + 0) = o0;
            *(float4*)(orow + 4) = o1;
        }
    }
}

// ---------------------------------------------------------------------------
extern "C" void kernel_launch(void* const* d_in, const int* in_sizes, int n_in,
                              void* d_out, int out_size, void* d_ws, size_t ws_size,
                              hipStream_t stream)
{
    const float* x  = (const float*)d_in[0];
    const float* Wq = (const float*)d_in[1];
    const float* bq = (const float*)d_in[2];
    const float* Wk = (const float*)d_in[3];
    const float* bk = (const float*)d_in[4];
    const float* Wv = (const float*)d_in[5];
    const float* bv = (const float*)d_in[6];
    float* out = (float*)d_out;

    // workspace: q,k,v fp32 [3][16384][128] = 25.2 MB
    float* qkv = (float*)d_ws;

    qkv_proj<<<dim3(NROWS / 128, 3), 256, 0, stream>>>(x, Wq, bq, Wk, bk, Wv, bv, qkv);

    const float* Qp = qkv;
    const float* Kp = qkv + (size_t)NROWS * HD;
    const float* Vp = qkv + (size_t)2 * NROWS * HD;
    flash_attn<<<dim3(BATCH * 64), 256, 0, stream>>>(Qp, Kp, Vp, out);
}

// Round 2
// 1069.417 us; speedup vs baseline: 10.1562x; 10.1562x over previous
//
#include <hip/hip_runtime.h>
#include <math.h>

// Problem constants
#define BATCH 4
#define SEQ   4096
#define HID   2048
#define HD    128
#define NROWS (BATCH*SEQ)          // 16384

static constexpr float OSCALE = 0.088388347648318447f;  // 1/sqrt(128), applied post-softmax

// ---------------------------------------------------------------------------
// QKV projection: out_m[r][d] = x[r][:] . W_m[:][d] + b_m[d]
// C tile 128x128 (blockIdx.y picks the matrix), BK=16, 256 threads, 8x8/thread
// ---------------------------------------------------------------------------
__global__ __launch_bounds__(256) void qkv_proj(
    const float* __restrict__ x,
    const float* __restrict__ Wq, const float* __restrict__ bq,
    const float* __restrict__ Wk, const float* __restrict__ bk,
    const float* __restrict__ Wv, const float* __restrict__ bv,
    float* __restrict__ qkv)
{
    __shared__ float As[16][132];   // [k][row]
    __shared__ float Bs[16][132];   // [k][col]

    const int tid = threadIdx.x;
    const int r0  = blockIdx.x * 128;
    const int mm  = blockIdx.y;                    // 0=q 1=k 2=v
    const float* W    = (mm == 0) ? Wq : (mm == 1) ? Wk : Wv;
    const float* bias = (mm == 0) ? bq : (mm == 1) ? bk : bv;
    float* out = qkv + (size_t)mm * NROWS * HD;

    const int tm = tid >> 4;    // 0..15 -> rows tm*4 and 64+tm*4
    const int tn = tid & 15;    // 0..15 -> cols tn*4 and 64+tn*4

    float acc[8][8];
    #pragma unroll
    for (int i = 0; i < 8; ++i)
        #pragma unroll
        for (int j = 0; j < 8; ++j) acc[i][j] = 0.f;

    for (int k0 = 0; k0 < HID; k0 += 16) {
        float4 a[2], bw[2];
        #pragma unroll
        for (int i = 0; i < 2; ++i) {
            const int fi = i * 256 + tid;          // 0..511
            const int lr = fi >> 2;                // 0..127
            const int lc = (fi & 3) << 2;          // 0,4,8,12
            a[i] = *(const float4*)(x + (size_t)(r0 + lr) * HID + k0 + lc);
            const int br = fi >> 5;                // 0..15
            const int bn = (fi & 31) << 2;         // 0..124
            bw[i] = *(const float4*)(W + (size_t)(k0 + br) * HD + bn);
        }
        __syncthreads();   // previous tile's readers done
        #pragma unroll
        for (int i = 0; i < 2; ++i) {
            const int fi = i * 256 + tid;
            const int lr = fi >> 2;
            const int lc = (fi & 3) << 2;
            As[lc + 0][lr] = a[i].x;
            As[lc + 1][lr] = a[i].y;
            As[lc + 2][lr] = a[i].z;
            As[lc + 3][lr] = a[i].w;
            const int br = fi >> 5;
            const int bn = (fi & 31) << 2;
            *(float4*)&Bs[br][bn] = bw[i];
        }
        __syncthreads();
        #pragma unroll
        for (int kk = 0; kk < 16; ++kk) {
            float av[8], bv2[8];
            *(float4*)&av[0]  = *(const float4*)&As[kk][tm * 4];
            *(float4*)&av[4]  = *(const float4*)&As[kk][64 + tm * 4];
            *(float4*)&bv2[0] = *(const float4*)&Bs[kk][tn * 4];
            *(float4*)&bv2[4] = *(const float4*)&Bs[kk][64 + tn * 4];
            #pragma unroll
            for (int i = 0; i < 8; ++i)
                #pragma unroll
                for (int j = 0; j < 8; ++j)
                    acc[i][j] = fmaf(av[i], bv2[j], acc[i][j]);
        }
        __syncthreads();
    }

    #pragma unroll
    for (int i = 0; i < 8; ++i) {
        const int r = r0 + ((i < 4) ? (tm * 4 + i) : (64 + tm * 4 + (i - 4)));
        float* orow = out + (size_t)r * HD;
        const int c0 = tn * 4, c1 = 64 + tn * 4;
        float4 s0, s1;
        s0.x = acc[i][0] + bias[c0 + 0];
        s0.y = acc[i][1] + bias[c0 + 1];
        s0.z = acc[i][2] + bias[c0 + 2];
        s0.w = acc[i][3] + bias[c0 + 3];
        s1.x = acc[i][4] + bias[c1 + 0];
        s1.y = acc[i][5] + bias[c1 + 1];
        s1.z = acc[i][6] + bias[c1 + 2];
        s1.w = acc[i][7] + bias[c1 + 3];
        *(float4*)(orow + c0) = s0;
        *(float4*)(orow + c1) = s1;
    }
}

// ---------------------------------------------------------------------------
// Flash attention, fp32, causal, NO qk scaling, output scaled by 1/sqrt(D).
// BQ=32 q rows per tile, BK=64 kv rows per tile.
// 256 threads: rg = tid>>4 (owns rows rg, rg+16), cg = tid&15.
//   scores: thread computes 2 rows x 4 cols (cols cg+16*i)
//   PV:     thread computes 2 rows x 8 dims (dims cg*8..cg*8+7)
// One block handles q-tiles {pair, 127-pair} -> uniform work (129 kv32-steps).
// NOTE: all private arrays MUST be indexed with compile-time constants —
// a per-lane runtime index demotes the array to scratch (R1 post-mortem:
// 10.5 ms -> the qp=(qi+cg)&1 swizzle put o[][] in scratch memory).
// ---------------------------------------------------------------------------
__global__ __launch_bounds__(256) void flash_attn(
    const float* __restrict__ Qm, const float* __restrict__ Km,
    const float* __restrict__ Vm, float* __restrict__ Out)
{
    __shared__ float Qs[32][132];
    __shared__ float Ks[64][132];
    __shared__ float Vs[64][132];
    __shared__ float Ps[32][68];

    const int tid  = threadIdx.x;
    const int rg   = tid >> 4;      // 0..15
    const int cg   = tid & 15;      // 0..15
    const int b    = blockIdx.x >> 6;
    const int pair = blockIdx.x & 63;

    for (int half = 0; half < 2; ++half) {
        const int t = half ? (127 - pair) : pair;
        const size_t qrow0 = (size_t)b * SEQ + (size_t)t * 32;

        __syncthreads();   // previous half's LDS readers done
        #pragma unroll
        for (int i = 0; i < 4; ++i) {
            const int fi = i * 256 + tid;      // 0..1023
            const int lr = fi >> 5;            // 0..31
            const int lc = (fi & 31) << 2;     // 0..124
            *(float4*)&Qs[lr][lc] = *(const float4*)(Qm + (qrow0 + lr) * HD + lc);
        }
        __syncthreads();

        float o[2][8];
        #pragma unroll
        for (int rr = 0; rr < 2; ++rr)
            #pragma unroll
            for (int d = 0; d < 8; ++d) o[rr][d] = 0.f;
        float mrow[2] = { -INFINITY, -INFINITY };
        float lrow[2] = { 0.f, 0.f };

        const int jmax = t >> 1;   // kv tiles 0..jmax (64-wide)

        for (int j = 0; j <= jmax; ++j) {
            // ---- stage K,V tile ----
            #pragma unroll
            for (int i = 0; i < 8; ++i) {
                const int fi = i * 256 + tid;  // 0..2047
                const int lr = fi >> 5;        // 0..63
                const int lc = (fi & 31) << 2;
                const size_t gb = ((size_t)b * SEQ + (size_t)j * 64 + lr) * HD + lc;
                *(float4*)&Ks[lr][lc] = *(const float4*)(Km + gb);
                *(float4*)&Vs[lr][lc] = *(const float4*)(Vm + gb);
            }
            __syncthreads();

            // ---- scores: 2 rows x 4 cols per thread ----
            float s[2][4];
            #pragma unroll
            for (int rr = 0; rr < 2; ++rr)
                #pragma unroll
                for (int i = 0; i < 4; ++i) s[rr][i] = 0.f;

            #pragma unroll 8
            for (int kk = 0; kk < 32; ++kk) {
                const float4 q0 = *(const float4*)&Qs[rg][kk << 2];
                const float4 q1 = *(const float4*)&Qs[rg + 16][kk << 2];
                #pragma unroll
                for (int i = 0; i < 4; ++i) {
                    const float4 kf = *(const float4*)&Ks[cg + 16 * i][kk << 2];
                    s[0][i] = fmaf(q0.x, kf.x, s[0][i]);
                    s[0][i] = fmaf(q0.y, kf.y, s[0][i]);
                    s[0][i] = fmaf(q0.z, kf.z, s[0][i]);
                    s[0][i] = fmaf(q0.w, kf.w, s[0][i]);
                    s[1][i] = fmaf(q1.x, kf.x, s[1][i]);
                    s[1][i] = fmaf(q1.y, kf.y, s[1][i]);
                    s[1][i] = fmaf(q1.z, kf.z, s[1][i]);
                    s[1][i] = fmaf(q1.w, kf.w, s[1][i]);
                }
            }

            if (j == jmax) {   // only the last tile can cross the diagonal
                #pragma unroll
                for (int rr = 0; rr < 2; ++rr) {
                    const int qidx = t * 32 + rg + 16 * rr;
                    #pragma unroll
                    for (int i = 0; i < 4; ++i) {
                        const int kidx = j * 64 + cg + 16 * i;
                        if (kidx > qidx) s[rr][i] = -INFINITY;
                    }
                }
            }

            // ---- online softmax (per row, reduce across the 16 cg lanes) ----
            #pragma unroll
            for (int rr = 0; rr < 2; ++rr) {
                float mt = fmaxf(fmaxf(s[rr][0], s[rr][1]), fmaxf(s[rr][2], s[rr][3]));
                mt = fmaxf(mt, __shfl_xor(mt, 1));
                mt = fmaxf(mt, __shfl_xor(mt, 2));
                mt = fmaxf(mt, __shfl_xor(mt, 4));
                mt = fmaxf(mt, __shfl_xor(mt, 8));
                const float mn    = fmaxf(mrow[rr], mt);
                const float alpha = __expf(mrow[rr] - mn);   // exp(-inf)=0 on first tile
                mrow[rr] = mn;
                float p[4], ps = 0.f;
                #pragma unroll
                for (int i = 0; i < 4; ++i) { p[i] = __expf(s[rr][i] - mn); ps += p[i]; }
                #pragma unroll
                for (int i = 0; i < 4; ++i) Ps[rg + 16 * rr][cg + 16 * i] = p[i];
                ps += __shfl_xor(ps, 1);
                ps += __shfl_xor(ps, 2);
                ps += __shfl_xor(ps, 4);
                ps += __shfl_xor(ps, 8);
                lrow[rr] = lrow[rr] * alpha + ps;
                #pragma unroll
                for (int d = 0; d < 8; ++d) o[rr][d] *= alpha;
            }
            __syncthreads();   // Ps visible to all

            // ---- PV: 2 rows x 8 dims per thread (ALL indices compile-time) ----
            #pragma unroll 4
            for (int c = 0; c < 64; ++c) {
                const float p0 = Ps[rg][c];
                const float p1 = Ps[rg + 16][c];
                const float4 v0 = *(const float4*)&Vs[c][cg * 8];
                const float4 v1 = *(const float4*)&Vs[c][cg * 8 + 4];
                o[0][0] = fmaf(p0, v0.x, o[0][0]);
                o[0][1] = fmaf(p0, v0.y, o[0][1]);
                o[0][2] = fmaf(p0, v0.z, o[0][2]);
                o[0][3] = fmaf(p0, v0.w, o[0][3]);
                o[0][4] = fmaf(p0, v1.x, o[0][4]);
                o[0][5] = fmaf(p0, v1.y, o[0][5]);
                o[0][6] = fmaf(p0, v1.z, o[0][6]);
                o[0][7] = fmaf(p0, v1.w, o[0][7]);
                o[1][0] = fmaf(p1, v0.x, o[1][0]);
                o[1][1] = fmaf(p1, v0.y, o[1][1]);
                o[1][2] = fmaf(p1, v0.z, o[1][2]);
                o[1][3] = fmaf(p1, v0.w, o[1][3]);
                o[1][4] = fmaf(p1, v1.x, o[1][4]);
                o[1][5] = fmaf(p1, v1.y, o[1][5]);
                o[1][6] = fmaf(p1, v1.z, o[1][6]);
                o[1][7] = fmaf(p1, v1.w, o[1][7]);
            }
            __syncthreads();   // done with Ks/Vs/Ps for this tile
        }

        // ---- epilogue: out = (softmax @ V) * 1/sqrt(D) ----
        #pragma unroll
        for (int rr = 0; rr < 2; ++rr) {
            const float inv = OSCALE / lrow[rr];
            float* orow = Out + (qrow0 + rg + 16 * rr) * HD + cg * 8;
            float4 o0, o1;
            o0.x = o[rr][0] * inv; o0.y = o[rr][1] * inv;
            o0.z = o[rr][2] * inv; o0.w = o[rr][3] * inv;
            o1.x = o[rr][4] * inv; o1.y = o[rr][5] * inv;
            o1.z = o[rr][6] * inv; o1.w = o[rr][7] * inv;
            *(float4*)(orow + 0) = o0;
            *(float4*)(orow + 4) = o1;
        }
    }
}

// ---------------------------------------------------------------------------
extern "C" void kernel_launch(void* const* d_in, const int* in_sizes, int n_in,
                              void* d_out, int out_size, void* d_ws, size_t ws_size,
                              hipStream_t stream)
{
    const float* x  = (const float*)d_in[0];
    const float* Wq = (const float*)d_in[1];
    const float* bq = (const float*)d_in[2];
    const float* Wk = (const float*)d_in[3];
    const float* bk = (const float*)d_in[4];
    const float* Wv = (const float*)d_in[5];
    const float* bv = (const float*)d_in[6];
    float* out = (float*)d_out;

    // workspace: q,k,v fp32 [3][16384][128] = 25.2 MB
    float* qkv = (float*)d_ws;

    qkv_proj<<<dim3(NROWS / 128, 3), 256, 0, stream>>>(x, Wq, bq, Wk, bk, Wv, bv, qkv);

    const float* Qp = qkv;
    const float* Kp = qkv + (size_t)NROWS * HD;
    const float* Vp = qkv + (size_t)2 * NROWS * HD;
    flash_attn<<<dim3(BATCH * 64), 256, 0, stream>>>(Qp, Kp, Vp, out);
}

// Round 3
// 395.126 us; speedup vs baseline: 27.4881x; 2.7065x over previous
//
#include <hip/hip_runtime.h>
#include <math.h>
#include <stdint.h>

#define SEQ   4096
#define HID   2048
#define HD    128
#define NROWS 16384          // BATCH*SEQ, BATCH=4

typedef __attribute__((ext_vector_type(8))) short bf16x8;   // 8 bf16 = 4 VGPRs
typedef __attribute__((ext_vector_type(4))) float f32x4;

static constexpr float OSCALE = 0.088388347648318447f;  // 1/sqrt(128), post-softmax

// ---- async global->LDS, 16B per lane; LDS dest = wave-uniform base + lane*16
using gvptr = const __attribute__((address_space(1))) void*;
using lvptr = __attribute__((address_space(3))) void*;
__device__ __forceinline__ void gld_lds16(const void* g, void* l) {
    __builtin_amdgcn_global_load_lds((gvptr)g, (lvptr)l, 16, 0, 0);
}

// ---- bf16 helpers (manual: storage is ushort)
__device__ __forceinline__ unsigned short f2bf_rne(float f) {
    union { float f; unsigned u; } v; v.f = f;
    unsigned u = v.u + 0x7fffu + ((v.u >> 16) & 1u);
    return (unsigned short)(u >> 16);
}
__device__ __forceinline__ unsigned short f2bf_tr(float f) {
    union { float f; unsigned u; } v; v.f = f;
    return (unsigned short)(v.u >> 16);
}
__device__ __forceinline__ float bf2f(unsigned short h) {
    union { unsigned u; float f; } v; v.u = ((unsigned)h) << 16;
    return v.f;
}

// ---------------------------------------------------------------------------
// prep_w: W[k][n] fp32 -> transposed bf16 hi/lo Wt[n][k] per matrix.
// grid (32 k-tiles, 2 n-tiles, 3 mats), 256 threads.
// ---------------------------------------------------------------------------
__global__ __launch_bounds__(256) void prep_w(
    const float* __restrict__ Wq, const float* __restrict__ Wk, const float* __restrict__ Wv,
    unsigned short* __restrict__ wth, unsigned short* __restrict__ wtl)
{
    __shared__ float T[64][68];
    const int tid = threadIdx.x;
    const int k0 = blockIdx.x * 64, n0 = blockIdx.y * 64, mm = blockIdx.z;
    const float* W = (mm == 0) ? Wq : (mm == 1) ? Wk : Wv;
    #pragma unroll
    for (int i = 0; i < 4; ++i) {
        const int fi = i * 256 + tid, kk = fi >> 4, nc = (fi & 15) * 4;
        const float4 w = *(const float4*)(W + (size_t)(k0 + kk) * HD + n0 + nc);
        T[kk][nc] = w.x; T[kk][nc + 1] = w.y; T[kk][nc + 2] = w.z; T[kk][nc + 3] = w.w;
    }
    __syncthreads();
    unsigned short* oh = wth + (size_t)mm * HD * HID;
    unsigned short* ol = wtl + (size_t)mm * HD * HID;
    #pragma unroll
    for (int i = 0; i < 4; ++i) {
        const int fi = i * 256 + tid, nn = fi >> 4, kc = (fi & 15) * 4;
        const float a = T[kc][nn], b = T[kc + 1][nn], c = T[kc + 2][nn], d = T[kc + 3][nn];
        ushort4 hv, lv;
        hv.x = f2bf_rne(a); hv.y = f2bf_rne(b); hv.z = f2bf_rne(c); hv.w = f2bf_rne(d);
        lv.x = f2bf_rne(a - bf2f(hv.x)); lv.y = f2bf_rne(b - bf2f(hv.y));
        lv.z = f2bf_rne(c - bf2f(hv.z)); lv.w = f2bf_rne(d - bf2f(hv.w));
        *(ushort4*)(oh + (size_t)(n0 + nn) * HID + k0 + kc) = hv;
        *(ushort4*)(ol + (size_t)(n0 + nn) * HID + k0 + kc) = lv;
    }
}

// ---------------------------------------------------------------------------
// qkv_mfma: out = x @ W + b via 16x16x32 bf16 MFMA with hi/lo split.
// grid (128 row-tiles, 3 mats), 256 threads = 4 waves in 2x2 (64x64 each).
// Q/K: 3 passes (hh+hl+lh); V: 1 pass (error budget allows).
// Emits: qh,ql,kh,kl [r][d] bf16; V transposed vth[b][d][s] bf16.
// ---------------------------------------------------------------------------
__global__ __launch_bounds__(256, 2) void qkv_mfma(
    const float* __restrict__ x,
    const float* __restrict__ bq, const float* __restrict__ bk, const float* __restrict__ bv,
    const unsigned short* __restrict__ wth, const unsigned short* __restrict__ wtl,
    unsigned short* __restrict__ qh, unsigned short* __restrict__ ql,
    unsigned short* __restrict__ kh, unsigned short* __restrict__ kl,
    unsigned short* __restrict__ vth)
{
    __shared__ unsigned short Ah[128][40], Al[128][40];   // padded (ds-written)
    __shared__ unsigned short Bh[128][32], Bl[128][32];   // unpadded (global_load_lds)

    const int tid = threadIdx.x, wave = tid >> 6, lane = tid & 63;
    const int l15 = lane & 15, q4 = lane >> 4;
    const int wr = wave >> 1, wc = wave & 1;
    const int r0 = blockIdx.x * 128, mm = blockIdx.y;
    const int npass = (mm == 2) ? 1 : 3;
    const unsigned short* wt_h = wth + (size_t)mm * HD * HID;
    const unsigned short* wt_l = wtl + (size_t)mm * HD * HID;

    f32x4 acc[4][4];
    #pragma unroll
    for (int i = 0; i < 4; ++i)
        #pragma unroll
        for (int j = 0; j < 4; ++j) acc[i][j] = (f32x4){0.f, 0.f, 0.f, 0.f};

    for (int k0 = 0; k0 < HID; k0 += 32) {
        float4 xv[4];
        #pragma unroll
        for (int i = 0; i < 4; ++i) {
            const int fi = i * 256 + tid, row = fi >> 3, kc = (fi & 7) * 4;
            xv[i] = *(const float4*)(x + (size_t)(r0 + row) * HID + k0 + kc);
        }
        __syncthreads();   // prior iteration's frag reads done
        {   // stage W tiles: rows = output cols n, 64B rows; wave stages 32 rows
            const int row = wave * 32 + (lane >> 2);
            const int col = (lane & 3) * 8;
            gld_lds16(wt_h + (size_t)row * HID + k0 + col, &Bh[wave * 32][0]);
            gld_lds16(wt_h + (size_t)(row + 16) * HID + k0 + col, &Bh[wave * 32 + 16][0]);
            if (npass == 3) {
                gld_lds16(wt_l + (size_t)row * HID + k0 + col, &Bl[wave * 32][0]);
                gld_lds16(wt_l + (size_t)(row + 16) * HID + k0 + col, &Bl[wave * 32 + 16][0]);
            }
        }
        #pragma unroll
        for (int i = 0; i < 4; ++i) {   // x fp32 -> bf16 hi/lo -> LDS
            const int fi = i * 256 + tid, row = fi >> 3, kc = (fi & 7) * 4;
            ushort4 hv, lv;
            hv.x = f2bf_tr(xv[i].x); hv.y = f2bf_tr(xv[i].y);
            hv.z = f2bf_tr(xv[i].z); hv.w = f2bf_tr(xv[i].w);
            *(ushort4*)&Ah[row][kc] = hv;
            if (npass == 3) {
                lv.x = f2bf_tr(xv[i].x - bf2f(hv.x)); lv.y = f2bf_tr(xv[i].y - bf2f(hv.y));
                lv.z = f2bf_tr(xv[i].z - bf2f(hv.z)); lv.w = f2bf_tr(xv[i].w - bf2f(hv.w));
                *(ushort4*)&Al[row][kc] = lv;
            }
        }
        __syncthreads();

        bf16x8 ah[4], bh_[4];
        #pragma unroll
        for (int t = 0; t < 4; ++t) {
            ah[t]  = *(const bf16x8*)&Ah[wr * 64 + t * 16 + l15][q4 * 8];
            bh_[t] = *(const bf16x8*)&Bh[wc * 64 + t * 16 + l15][q4 * 8];
        }
        if (npass == 3) {
            bf16x8 al[4], bl_[4];
            #pragma unroll
            for (int t = 0; t < 4; ++t) {
                al[t]  = *(const bf16x8*)&Al[wr * 64 + t * 16 + l15][q4 * 8];
                bl_[t] = *(const bf16x8*)&Bl[wc * 64 + t * 16 + l15][q4 * 8];
            }
            #pragma unroll
            for (int mt = 0; mt < 4; ++mt)
                #pragma unroll
                for (int nt = 0; nt < 4; ++nt) {
                    acc[mt][nt] = __builtin_amdgcn_mfma_f32_16x16x32_bf16(ah[mt], bh_[nt], acc[mt][nt], 0, 0, 0);
                    acc[mt][nt] = __builtin_amdgcn_mfma_f32_16x16x32_bf16(ah[mt], bl_[nt], acc[mt][nt], 0, 0, 0);
                    acc[mt][nt] = __builtin_amdgcn_mfma_f32_16x16x32_bf16(al[mt], bh_[nt], acc[mt][nt], 0, 0, 0);
                }
        } else {
            #pragma unroll
            for (int mt = 0; mt < 4; ++mt)
                #pragma unroll
                for (int nt = 0; nt < 4; ++nt)
                    acc[mt][nt] = __builtin_amdgcn_mfma_f32_16x16x32_bf16(ah[mt], bh_[nt], acc[mt][nt], 0, 0, 0);
        }
    }

    // epilogue: +bias, split/store. C-frag: col=l15(+tile), rows=q4*4+reg.
    const float* bias = (mm == 0) ? bq : (mm == 1) ? bk : bv;
    if (mm < 2) {
        unsigned short* oh = (mm == 0) ? qh : kh;
        unsigned short* ol = (mm == 0) ? ql : kl;
        #pragma unroll
        for (int nt = 0; nt < 4; ++nt) {
            const int col = wc * 64 + nt * 16 + l15;
            const float bb = bias[col];
            #pragma unroll
            for (int mt = 0; mt < 4; ++mt) {
                const int Rb = r0 + wr * 64 + mt * 16 + q4 * 4;
                #pragma unroll
                for (int r = 0; r < 4; ++r) {
                    const float v = acc[mt][nt][r] + bb;
                    const unsigned short hh = f2bf_rne(v);
                    oh[(size_t)(Rb + r) * HD + col] = hh;
                    ol[(size_t)(Rb + r) * HD + col] = f2bf_rne(v - bf2f(hh));
                }
            }
        }
    } else {
        #pragma unroll
        for (int nt = 0; nt < 4; ++nt) {
            const int col = wc * 64 + nt * 16 + l15;
            const float bb = bias[col];
            #pragma unroll
            for (int mt = 0; mt < 4; ++mt) {
                const int Rb = r0 + wr * 64 + mt * 16 + q4 * 4;
                const int bi = Rb >> 12, s0 = Rb & 4095;   // regs = consecutive s
                ushort4 pv;
                pv.x = f2bf_rne(acc[mt][nt][0] + bb);
                pv.y = f2bf_rne(acc[mt][nt][1] + bb);
                pv.z = f2bf_rne(acc[mt][nt][2] + bb);
                pv.w = f2bf_rne(acc[mt][nt][3] + bb);
                *(ushort4*)(vth + ((size_t)(bi * HD + col)) * SEQ + s0) = pv;
            }
        }
    }
}

// ---------------------------------------------------------------------------
// flash_mfma: causal flash attention on MFMA. BQ=64 (wave owns 16-row stripe,
// wave-local online softmax), BK=64. Grid: 4b x 32 pairs(t,63-t) x 2 kv-halves
// = 256 uniform blocks; partials merged by flash_merge.
// ---------------------------------------------------------------------------
__global__ __launch_bounds__(256, 2) void flash_mfma(
    const unsigned short* __restrict__ qh, const unsigned short* __restrict__ ql,
    const unsigned short* __restrict__ kh, const unsigned short* __restrict__ kl,
    const unsigned short* __restrict__ vth,
    float* __restrict__ oP, float* __restrict__ mP, float* __restrict__ lP)
{
    __shared__ unsigned short Kh[64][128], Kl[64][128];   // [kvrow][d]
    __shared__ unsigned short Vt[128][64];                // [d][kvrow]
    __shared__ unsigned short Ps[4][16][72];              // per-wave P, padded

    const int tid = threadIdx.x, wave = tid >> 6, lane = tid & 63;
    const int l15 = lane & 15, q4 = lane >> 4;
    const int h = blockIdx.x & 1, pair = (blockIdx.x >> 1) & 31, b = blockIdx.x >> 6;

    for (int side = 0; side < 2; ++side) {
        const int tt = side ? (63 - pair) : pair;
        const int j0 = h ? ((tt + 2) >> 1) : 0;
        const int j1 = h ? (tt + 1) : ((tt + 2) >> 1);

        // Q A-frags in registers (A[m=lane&15][k=quad*8+j]), hi+lo
        const int qrow = b * SEQ + tt * 64 + wave * 16 + l15;
        bf16x8 aqh[4], aql[4];
        #pragma unroll
        for (int ks = 0; ks < 4; ++ks) {
            aqh[ks] = *(const bf16x8*)(qh + (size_t)qrow * HD + ks * 32 + q4 * 8);
            aql[ks] = *(const bf16x8*)(ql + (size_t)qrow * HD + ks * 32 + q4 * 8);
        }
        f32x4 oa[8];
        #pragma unroll
        for (int d = 0; d < 8; ++d) oa[d] = (f32x4){0.f, 0.f, 0.f, 0.f};
        float m_r[4] = {-INFINITY, -INFINITY, -INFINITY, -INFINITY};
        float l_r[4] = {0.f, 0.f, 0.f, 0.f};

        for (int j = j0; j < j1; ++j) {
            __syncthreads();   // prior tile's LDS readers done
            {   // stage K hi/lo ([64][128], 256B rows) and Vt ([128][64], 128B rows)
                const size_t kb = (size_t)b * SEQ + j * 64;
                const int krow = wave * 16 + (lane >> 4), kcol = l15 * 8;
                #pragma unroll
                for (int c = 0; c < 4; ++c) {
                    gld_lds16(kh + (kb + krow + c * 4) * HD + kcol, &Kh[wave * 16 + c * 4][0]);
                    gld_lds16(kl + (kb + krow + c * 4) * HD + kcol, &Kl[wave * 16 + c * 4][0]);
                }
                const int vrow = wave * 32 + (lane >> 3), vcol = (lane & 7) * 8;
                #pragma unroll
                for (int c = 0; c < 4; ++c)
                    gld_lds16(vth + ((size_t)(b * HD + vrow + c * 8)) * SEQ + j * 64 + vcol,
                              &Vt[wave * 32 + c * 8][0]);
            }
            __syncthreads();

            // QK^T: B-frag lane holds K[n0+l15][quad*8+j] (native rows)
            f32x4 s[4];
            #pragma unroll
            for (int nt = 0; nt < 4; ++nt) s[nt] = (f32x4){0.f, 0.f, 0.f, 0.f};
            #pragma unroll
            for (int ks = 0; ks < 4; ++ks) {
                #pragma unroll
                for (int nt = 0; nt < 4; ++nt) {
                    const bf16x8 bh = *(const bf16x8*)&Kh[nt * 16 + l15][ks * 32 + q4 * 8];
                    const bf16x8 bl = *(const bf16x8*)&Kl[nt * 16 + l15][ks * 32 + q4 * 8];
                    s[nt] = __builtin_amdgcn_mfma_f32_16x16x32_bf16(aqh[ks], bh, s[nt], 0, 0, 0);
                    s[nt] = __builtin_amdgcn_mfma_f32_16x16x32_bf16(aql[ks], bh, s[nt], 0, 0, 0);
                    s[nt] = __builtin_amdgcn_mfma_f32_16x16x32_bf16(aqh[ks], bl, s[nt], 0, 0, 0);
                }
            }
            if (j == tt) {   // diagonal tile mask
                #pragma unroll
                for (int nt = 0; nt < 4; ++nt) {
                    const int cl = nt * 16 + l15;
                    #pragma unroll
                    for (int r = 0; r < 4; ++r) {
                        const int rl = wave * 16 + q4 * 4 + r;
                        if (cl > rl) s[nt][r] = -INFINITY;
                    }
                }
            }
            // online softmax: row r lives in the quad's 16 lanes (shfl_xor<=8)
            #pragma unroll
            for (int r = 0; r < 4; ++r) {
                float mt = fmaxf(fmaxf(s[0][r], s[1][r]), fmaxf(s[2][r], s[3][r]));
                mt = fmaxf(mt, __shfl_xor(mt, 1));
                mt = fmaxf(mt, __shfl_xor(mt, 2));
                mt = fmaxf(mt, __shfl_xor(mt, 4));
                mt = fmaxf(mt, __shfl_xor(mt, 8));
                const float mn = fmaxf(m_r[r], mt);
                const float al = __expf(m_r[r] - mn);
                m_r[r] = mn;
                const float p0 = __expf(s[0][r] - mn), p1 = __expf(s[1][r] - mn);
                const float p2 = __expf(s[2][r] - mn), p3 = __expf(s[3][r] - mn);
                Ps[wave][q4 * 4 + r][l15]      = f2bf_tr(p0);
                Ps[wave][q4 * 4 + r][16 + l15] = f2bf_tr(p1);
                Ps[wave][q4 * 4 + r][32 + l15] = f2bf_tr(p2);
                Ps[wave][q4 * 4 + r][48 + l15] = f2bf_tr(p3);
                float ps = p0 + p1 + p2 + p3;
                ps += __shfl_xor(ps, 1); ps += __shfl_xor(ps, 2);
                ps += __shfl_xor(ps, 4); ps += __shfl_xor(ps, 8);
                l_r[r] = l_r[r] * al + ps;
                #pragma unroll
                for (int d = 0; d < 8; ++d) oa[d][r] *= al;
            }
            // PV: A=P from own wave's LDS (no barrier needed), B from Vt
            const bf16x8 ap0 = *(const bf16x8*)&Ps[wave][l15][q4 * 8];
            const bf16x8 ap1 = *(const bf16x8*)&Ps[wave][l15][32 + q4 * 8];
            #pragma unroll
            for (int d = 0; d < 8; ++d) {
                const bf16x8 bv0 = *(const bf16x8*)&Vt[d * 16 + l15][q4 * 8];
                const bf16x8 bv1 = *(const bf16x8*)&Vt[d * 16 + l15][32 + q4 * 8];
                oa[d] = __builtin_amdgcn_mfma_f32_16x16x32_bf16(ap0, bv0, oa[d], 0, 0, 0);
                oa[d] = __builtin_amdgcn_mfma_f32_16x16x32_bf16(ap1, bv1, oa[d], 0, 0, 0);
            }
        }

        // write partials (unnormalized o, running m,l)
        const int R0 = b * SEQ + tt * 64 + wave * 16 + q4 * 4;
        float* op = oP + (size_t)h * NROWS * HD;
        #pragma unroll
        for (int d = 0; d < 8; ++d)
            #pragma unroll
            for (int r = 0; r < 4; ++r)
                op[(size_t)(R0 + r) * HD + d * 16 + l15] = oa[d][r];
        if (l15 == 0) {
            #pragma unroll
            for (int r = 0; r < 4; ++r) {
                mP[h * NROWS + R0 + r] = m_r[r];
                lP[h * NROWS + R0 + r] = l_r[r];
            }
        }
    }
}

// ---------------------------------------------------------------------------
// merge the two kv-half partials; apply 1/l and OSCALE.
// ---------------------------------------------------------------------------
__global__ __launch_bounds__(256) void flash_merge(
    const float* __restrict__ oP, const float* __restrict__ mP, const float* __restrict__ lP,
    float* __restrict__ out)
{
    const int idx = blockIdx.x * 256 + threadIdx.x;   // per float4
    const int r = idx >> 5, c = (idx & 31) * 4;
    const float m0 = mP[r], m1 = mP[NROWS + r];
    const float l0 = lP[r], l1 = lP[NROWS + r];
    const float M = fmaxf(m0, m1);
    const float a0 = __expf(m0 - M), a1 = __expf(m1 - M);
    const float inv = OSCALE / (l0 * a0 + l1 * a1);
    const float4 o0 = *(const float4*)(oP + (size_t)r * HD + c);
    const float4 o1 = *(const float4*)(oP + (size_t)(NROWS + r) * HD + c);
    float4 o;
    o.x = (o0.x * a0 + o1.x * a1) * inv;
    o.y = (o0.y * a0 + o1.y * a1) * inv;
    o.z = (o0.z * a0 + o1.z * a1) * inv;
    o.w = (o0.w * a0 + o1.w * a1) * inv;
    *(float4*)(out + (size_t)r * HD + c) = o;
}

// ---------------------------------------------------------------------------
extern "C" void kernel_launch(void* const* d_in, const int* in_sizes, int n_in,
                              void* d_out, int out_size, void* d_ws, size_t ws_size,
                              hipStream_t stream)
{
    (void)in_sizes; (void)n_in; (void)out_size; (void)ws_size;
    const float* x  = (const float*)d_in[0];
    const float* Wq = (const float*)d_in[1];
    const float* bq = (const float*)d_in[2];
    const float* Wk = (const float*)d_in[3];
    const float* bk = (const float*)d_in[4];
    const float* Wv = (const float*)d_in[5];
    const float* bv = (const float*)d_in[6];
    float* out = (float*)d_out;

    // workspace layout (bytes): 41.2 MB total
    char* w = (char*)d_ws;
    unsigned short* qh  = (unsigned short*)(w);
    unsigned short* ql  = (unsigned short*)(w + 4194304);
    unsigned short* kh  = (unsigned short*)(w + 8388608);
    unsigned short* kl  = (unsigned short*)(w + 12582912);
    unsigned short* vth = (unsigned short*)(w + 16777216);
    unsigned short* wth = (unsigned short*)(w + 20971520);
    unsigned short* wtl = (unsigned short*)(w + 22544384);
    float* oP = (float*)(w + 24117248);
    float* mP = (float*)(w + 40894464);
    float* lP = (float*)(w + 41025536);

    prep_w<<<dim3(32, 2, 3), 256, 0, stream>>>(Wq, Wk, Wv, wth, wtl);
    qkv_mfma<<<dim3(128, 3), 256, 0, stream>>>(x, bq, bk, bv, wth, wtl, qh, ql, kh, kl, vth);
    flash_mfma<<<256, 256, 0, stream>>>(qh, ql, kh, kl, vth, oP, mP, lP);
    flash_merge<<<2048, 256, 0, stream>>>(oP, mP, lP, out);
}

// Round 4
// 328.539 us; speedup vs baseline: 33.0592x; 1.2027x over previous
//
#include <hip/hip_runtime.h>
#include <math.h>
#include <stdint.h>

#define SEQ   4096
#define HID   2048
#define HD    128
#define NROWS 16384          // BATCH*SEQ, BATCH=4

typedef __attribute__((ext_vector_type(8))) short bf16x8;   // 8 bf16 = 4 VGPRs
typedef __attribute__((ext_vector_type(4))) float f32x4;

static constexpr float OSCALE = 0.088388347648318447f;  // 1/sqrt(128), post-softmax

// ---- async global->LDS, 16B per lane; LDS dest = wave-uniform base + lane*16.
// Global source address is per-lane -> we use it to XOR-swizzle chunk placement
// (R3 post-mortem: unswizzled 256B/128B/64B rows gave 16/16/8-way bank conflicts
//  = 3.65e7 conflict cycles = 44% of flash runtime).
using gvptr = const __attribute__((address_space(1))) void*;
using lvptr = __attribute__((address_space(3))) void*;
__device__ __forceinline__ void gld_lds16(const void* g, void* l) {
    __builtin_amdgcn_global_load_lds((gvptr)g, (lvptr)l, 16, 0, 0);
}

// ---- bf16 helpers (manual: storage is ushort)
__device__ __forceinline__ unsigned short f2bf_rne(float f) {
    union { float f; unsigned u; } v; v.f = f;
    unsigned u = v.u + 0x7fffu + ((v.u >> 16) & 1u);
    return (unsigned short)(u >> 16);
}
__device__ __forceinline__ unsigned short f2bf_tr(float f) {
    union { float f; unsigned u; } v; v.f = f;
    return (unsigned short)(v.u >> 16);
}
__device__ __forceinline__ float bf2f(unsigned short h) {
    union { unsigned u; float f; } v; v.u = ((unsigned)h) << 16;
    return v.f;
}

// ---------------------------------------------------------------------------
// prep_w: W[k][n] fp32 -> transposed bf16 hi/lo Wt[n][k] per matrix.
// ---------------------------------------------------------------------------
__global__ __launch_bounds__(256) void prep_w(
    const float* __restrict__ Wq, const float* __restrict__ Wk, const float* __restrict__ Wv,
    unsigned short* __restrict__ wth, unsigned short* __restrict__ wtl)
{
    __shared__ float T[64][68];
    const int tid = threadIdx.x;
    const int k0 = blockIdx.x * 64, n0 = blockIdx.y * 64, mm = blockIdx.z;
    const float* W = (mm == 0) ? Wq : (mm == 1) ? Wk : Wv;
    #pragma unroll
    for (int i = 0; i < 4; ++i) {
        const int fi = i * 256 + tid, kk = fi >> 4, nc = (fi & 15) * 4;
        const float4 w = *(const float4*)(W + (size_t)(k0 + kk) * HD + n0 + nc);
        T[kk][nc] = w.x; T[kk][nc + 1] = w.y; T[kk][nc + 2] = w.z; T[kk][nc + 3] = w.w;
    }
    __syncthreads();
    unsigned short* oh = wth + (size_t)mm * HD * HID;
    unsigned short* ol = wtl + (size_t)mm * HD * HID;
    #pragma unroll
    for (int i = 0; i < 4; ++i) {
        const int fi = i * 256 + tid, nn = fi >> 4, kc = (fi & 15) * 4;
        const float a = T[kc][nn], b = T[kc + 1][nn], c = T[kc + 2][nn], d = T[kc + 3][nn];
        ushort4 hv, lv;
        hv.x = f2bf_rne(a); hv.y = f2bf_rne(b); hv.z = f2bf_rne(c); hv.w = f2bf_rne(d);
        lv.x = f2bf_rne(a - bf2f(hv.x)); lv.y = f2bf_rne(b - bf2f(hv.y));
        lv.z = f2bf_rne(c - bf2f(hv.z)); lv.w = f2bf_rne(d - bf2f(hv.w));
        *(ushort4*)(oh + (size_t)(n0 + nn) * HID + k0 + kc) = hv;
        *(ushort4*)(ol + (size_t)(n0 + nn) * HID + k0 + kc) = lv;
    }
}

// ---------------------------------------------------------------------------
// qkv_mfma: out = x @ W + b via 16x16x32 bf16 MFMA with hi/lo split.
// grid (128 row-tiles, 3 mats), 4 waves 2x2. Q/K 3 passes, V 1 pass.
// B tiles (64B rows) staged with chunk ^= (row>>1)&3 swizzle -> 2-way reads.
// ---------------------------------------------------------------------------
__global__ __launch_bounds__(256, 2) void qkv_mfma(
    const float* __restrict__ x,
    const float* __restrict__ bq, const float* __restrict__ bk, const float* __restrict__ bv,
    const unsigned short* __restrict__ wth, const unsigned short* __restrict__ wtl,
    unsigned short* __restrict__ qh, unsigned short* __restrict__ ql,
    unsigned short* __restrict__ kh, unsigned short* __restrict__ kl,
    unsigned short* __restrict__ vth)
{
    __shared__ unsigned short Ah[128][40], Al[128][40];   // padded (ds-written)
    __shared__ unsigned short Bh[128][32], Bl[128][32];   // swizzled (global_load_lds)

    const int tid = threadIdx.x, wave = tid >> 6, lane = tid & 63;
    const int l15 = lane & 15, q4 = lane >> 4;
    const int wr = wave >> 1, wc = wave & 1;
    const int r0 = blockIdx.x * 128, mm = blockIdx.y;
    const int npass = (mm == 2) ? 1 : 3;
    const unsigned short* wt_h = wth + (size_t)mm * HD * HID;
    const unsigned short* wt_l = wtl + (size_t)mm * HD * HID;

    // staging lane mapping (16 rows x 4 chunks per gld): row=+lane>>2, phys=lane&3
    const int brow = lane >> 2;
    const int bsc  = ((lane & 3) ^ ((lane >> 3) & 3)) * 8;   // swizzled source chunk
    // frag-read swizzle key
    const int bkey = (l15 >> 1) & 3;

    f32x4 acc[4][4];
    #pragma unroll
    for (int i = 0; i < 4; ++i)
        #pragma unroll
        for (int j = 0; j < 4; ++j) acc[i][j] = (f32x4){0.f, 0.f, 0.f, 0.f};

    for (int k0 = 0; k0 < HID; k0 += 32) {
        float4 xv[4];
        #pragma unroll
        for (int i = 0; i < 4; ++i) {
            const int fi = i * 256 + tid, row = fi >> 3, kc = (fi & 7) * 4;
            xv[i] = *(const float4*)(x + (size_t)(r0 + row) * HID + k0 + kc);
        }
        __syncthreads();   // prior iteration's frag reads done
        {   // stage W tiles (swizzled): wave stages rows wave*32 .. +31
            const int rA = wave * 32 + brow, rB = rA + 16;
            gld_lds16(wt_h + (size_t)rA * HID + k0 + bsc, &Bh[wave * 32][0]);
            gld_lds16(wt_h + (size_t)rB * HID + k0 + bsc, &Bh[wave * 32 + 16][0]);
            if (npass == 3) {
                gld_lds16(wt_l + (size_t)rA * HID + k0 + bsc, &Bl[wave * 32][0]);
                gld_lds16(wt_l + (size_t)rB * HID + k0 + bsc, &Bl[wave * 32 + 16][0]);
            }
        }
        #pragma unroll
        for (int i = 0; i < 4; ++i) {   // x fp32 -> bf16 hi/lo -> LDS
            const int fi = i * 256 + tid, row = fi >> 3, kc = (fi & 7) * 4;
            ushort4 hv, lv;
            hv.x = f2bf_tr(xv[i].x); hv.y = f2bf_tr(xv[i].y);
            hv.z = f2bf_tr(xv[i].z); hv.w = f2bf_tr(xv[i].w);
            *(ushort4*)&Ah[row][kc] = hv;
            if (npass == 3) {
                lv.x = f2bf_tr(xv[i].x - bf2f(hv.x)); lv.y = f2bf_tr(xv[i].y - bf2f(hv.y));
                lv.z = f2bf_tr(xv[i].z - bf2f(hv.z)); lv.w = f2bf_tr(xv[i].w - bf2f(hv.w));
                *(ushort4*)&Al[row][kc] = lv;
            }
        }
        __syncthreads();

        bf16x8 ah[4], bh_[4];
        #pragma unroll
        for (int t = 0; t < 4; ++t) {
            ah[t]  = *(const bf16x8*)&Ah[wr * 64 + t * 16 + l15][q4 * 8];
            bh_[t] = *(const bf16x8*)&Bh[wc * 64 + t * 16 + l15][(q4 ^ bkey) * 8];
        }
        if (npass == 3) {
            bf16x8 al[4], bl_[4];
            #pragma unroll
            for (int t = 0; t < 4; ++t) {
                al[t]  = *(const bf16x8*)&Al[wr * 64 + t * 16 + l15][q4 * 8];
                bl_[t] = *(const bf16x8*)&Bl[wc * 64 + t * 16 + l15][(q4 ^ bkey) * 8];
            }
            #pragma unroll
            for (int mt = 0; mt < 4; ++mt)
                #pragma unroll
                for (int nt = 0; nt < 4; ++nt) {
                    acc[mt][nt] = __builtin_amdgcn_mfma_f32_16x16x32_bf16(ah[mt], bh_[nt], acc[mt][nt], 0, 0, 0);
                    acc[mt][nt] = __builtin_amdgcn_mfma_f32_16x16x32_bf16(ah[mt], bl_[nt], acc[mt][nt], 0, 0, 0);
                    acc[mt][nt] = __builtin_amdgcn_mfma_f32_16x16x32_bf16(al[mt], bh_[nt], acc[mt][nt], 0, 0, 0);
                }
        } else {
            #pragma unroll
            for (int mt = 0; mt < 4; ++mt)
                #pragma unroll
                for (int nt = 0; nt < 4; ++nt)
                    acc[mt][nt] = __builtin_amdgcn_mfma_f32_16x16x32_bf16(ah[mt], bh_[nt], acc[mt][nt], 0, 0, 0);
        }
    }

    // epilogue: +bias, split/store. C-frag: col=l15(+tile), rows=q4*4+reg.
    const float* bias = (mm == 0) ? bq : (mm == 1) ? bk : bv;
    if (mm < 2) {
        unsigned short* oh = (mm == 0) ? qh : kh;
        unsigned short* ol = (mm == 0) ? ql : kl;
        #pragma unroll
        for (int nt = 0; nt < 4; ++nt) {
            const int col = wc * 64 + nt * 16 + l15;
            const float bb = bias[col];
            #pragma unroll
            for (int mt = 0; mt < 4; ++mt) {
                const int Rb = r0 + wr * 64 + mt * 16 + q4 * 4;
                #pragma unroll
                for (int r = 0; r < 4; ++r) {
                    const float v = acc[mt][nt][r] + bb;
                    const unsigned short hh = f2bf_rne(v);
                    oh[(size_t)(Rb + r) * HD + col] = hh;
                    ol[(size_t)(Rb + r) * HD + col] = f2bf_rne(v - bf2f(hh));
                }
            }
        }
    } else {
        #pragma unroll
        for (int nt = 0; nt < 4; ++nt) {
            const int col = wc * 64 + nt * 16 + l15;
            const float bb = bias[col];
            #pragma unroll
            for (int mt = 0; mt < 4; ++mt) {
                const int Rb = r0 + wr * 64 + mt * 16 + q4 * 4;
                const int bi = Rb >> 12, s0 = Rb & 4095;   // regs = consecutive s
                ushort4 pv;
                pv.x = f2bf_rne(acc[mt][nt][0] + bb);
                pv.y = f2bf_rne(acc[mt][nt][1] + bb);
                pv.z = f2bf_rne(acc[mt][nt][2] + bb);
                pv.w = f2bf_rne(acc[mt][nt][3] + bb);
                *(ushort4*)(vth + ((size_t)(bi * HD + col)) * SEQ + s0) = pv;
            }
        }
    }
}

// ---------------------------------------------------------------------------
// flash_mfma: causal flash on MFMA. BQ=64 (wave-local softmax per 16-row
// stripe), BK=64. Grid: 4b x 32 pairs(t,63-t) x 4 kv-quarters = 512 blocks
// (2 blocks/CU resident). K/Vt LDS chunk-swizzled (^row&7) -> 2-way reads.
// Partials bf16 (4 quarters); merged by flash_merge.
// ---------------------------------------------------------------------------
__global__ __launch_bounds__(256, 2) void flash_mfma(
    const unsigned short* __restrict__ qh, const unsigned short* __restrict__ ql,
    const unsigned short* __restrict__ kh, const unsigned short* __restrict__ kl,
    const unsigned short* __restrict__ vth,
    unsigned short* __restrict__ oPb, float* __restrict__ mP, float* __restrict__ lP)
{
    __shared__ unsigned short Kh[64][128], Kl[64][128];   // [kvrow][d], swizzled
    __shared__ unsigned short Vt[128][64];                // [d][kvrow], swizzled
    __shared__ unsigned short Ps[4][16][72];              // per-wave P, padded

    const int tid = threadIdx.x, wave = tid >> 6, lane = tid & 63;
    const int l15 = lane & 15, q4 = lane >> 4;
    const int h = blockIdx.x & 3, pair = (blockIdx.x >> 2) & 31, b = blockIdx.x >> 7;

    // staging lane mapping for K (4 rows x 16 chunks per gld) and Vt (8 x 8)
    const int krow_l = lane >> 4;                               // 0..3
    const int vrow_l = lane >> 3;                               // 0..7
    const int vsc = ((lane & 7) ^ (vrow_l & 7)) * 8;            // Vt src chunk
    const int kkey7 = l15 & 7;                                  // K read swizzle
    const int vkey7 = l15 & 7;                                  // Vt read swizzle

    for (int side = 0; side < 2; ++side) {
        const int tt = side ? (63 - pair) : pair;
        const int n = tt + 1;
        const int j0 = (n * h) >> 2, j1 = (n * (h + 1)) >> 2;

        // Q A-frags in registers (A[m=lane&15][k=quad*8+j]), hi+lo
        const int qrow = b * SEQ + tt * 64 + wave * 16 + l15;
        bf16x8 aqh[4], aql[4];
        #pragma unroll
        for (int ks = 0; ks < 4; ++ks) {
            aqh[ks] = *(const bf16x8*)(qh + (size_t)qrow * HD + ks * 32 + q4 * 8);
            aql[ks] = *(const bf16x8*)(ql + (size_t)qrow * HD + ks * 32 + q4 * 8);
        }
        f32x4 oa[8];
        #pragma unroll
        for (int d = 0; d < 8; ++d) oa[d] = (f32x4){0.f, 0.f, 0.f, 0.f};
        float m_r[4] = {-INFINITY, -INFINITY, -INFINITY, -INFINITY};
        float l_r[4] = {0.f, 0.f, 0.f, 0.f};

        for (int j = j0; j < j1; ++j) {
            __syncthreads();   // prior tile's LDS readers done
            {   // stage K hi/lo + Vt, chunk-swizzled
                const size_t kb = (size_t)b * SEQ + j * 64;
                #pragma unroll
                for (int c = 0; c < 4; ++c) {
                    const int rl = c * 4 + krow_l;                  // row in tile (mod16)
                    const int sc = (l15 ^ (rl & 7)) * 8;            // swizzled src chunk
                    const size_t gr = (kb + wave * 16 + rl) * HD + sc;
                    gld_lds16(kh + gr, &Kh[wave * 16 + c * 4][0]);
                    gld_lds16(kl + gr, &Kl[wave * 16 + c * 4][0]);
                }
                #pragma unroll
                for (int c = 0; c < 4; ++c)
                    gld_lds16(vth + ((size_t)(b * HD + wave * 32 + c * 8 + vrow_l)) * SEQ
                                  + j * 64 + vsc,
                              &Vt[wave * 32 + c * 8][0]);
            }
            __syncthreads();

            // QK^T: B-frag lane holds K[n0+l15][quad*8+j] (swizzled chunks)
            f32x4 s[4];
            #pragma unroll
            for (int nt = 0; nt < 4; ++nt) s[nt] = (f32x4){0.f, 0.f, 0.f, 0.f};
            #pragma unroll
            for (int ks = 0; ks < 4; ++ks) {
                const int pc = ((ks * 4 + q4) ^ kkey7) * 8;
                #pragma unroll
                for (int nt = 0; nt < 4; ++nt) {
                    const bf16x8 bh = *(const bf16x8*)&Kh[nt * 16 + l15][pc];
                    const bf16x8 bl = *(const bf16x8*)&Kl[nt * 16 + l15][pc];
                    s[nt] = __builtin_amdgcn_mfma_f32_16x16x32_bf16(aqh[ks], bh, s[nt], 0, 0, 0);
                    s[nt] = __builtin_amdgcn_mfma_f32_16x16x32_bf16(aql[ks], bh, s[nt], 0, 0, 0);
                    s[nt] = __builtin_amdgcn_mfma_f32_16x16x32_bf16(aqh[ks], bl, s[nt], 0, 0, 0);
                }
            }
            if (j == tt) {   // diagonal tile mask
                #pragma unroll
                for (int nt = 0; nt < 4; ++nt) {
                    const int cl = nt * 16 + l15;
                    #pragma unroll
                    for (int r = 0; r < 4; ++r) {
                        const int rl = wave * 16 + q4 * 4 + r;
                        if (cl > rl) s[nt][r] = -INFINITY;
                    }
                }
            }
            // online softmax: row r lives in the quad's 16 lanes (shfl_xor<=8)
            #pragma unroll
            for (int r = 0; r < 4; ++r) {
                float mt = fmaxf(fmaxf(s[0][r], s[1][r]), fmaxf(s[2][r], s[3][r]));
                mt = fmaxf(mt, __shfl_xor(mt, 1));
                mt = fmaxf(mt, __shfl_xor(mt, 2));
                mt = fmaxf(mt, __shfl_xor(mt, 4));
                mt = fmaxf(mt, __shfl_xor(mt, 8));
                const float mn = fmaxf(m_r[r], mt);
                const float al = __expf(m_r[r] - mn);
                m_r[r] = mn;
                const float p0 = __expf(s[0][r] - mn), p1 = __expf(s[1][r] - mn);
                const float p2 = __expf(s[2][r] - mn), p3 = __expf(s[3][r] - mn);
                Ps[wave][q4 * 4 + r][l15]      = f2bf_tr(p0);
                Ps[wave][q4 * 4 + r][16 + l15] = f2bf_tr(p1);
                Ps[wave][q4 * 4 + r][32 + l15] = f2bf_tr(p2);
                Ps[wave][q4 * 4 + r][48 + l15] = f2bf_tr(p3);
                float ps = p0 + p1 + p2 + p3;
                ps += __shfl_xor(ps, 1); ps += __shfl_xor(ps, 2);
                ps += __shfl_xor(ps, 4); ps += __shfl_xor(ps, 8);
                l_r[r] = l_r[r] * al + ps;
                #pragma unroll
                for (int d = 0; d < 8; ++d) oa[d][r] *= al;
            }
            // PV: A=P from own wave's LDS (no barrier), B from swizzled Vt
            const bf16x8 ap0 = *(const bf16x8*)&Ps[wave][l15][q4 * 8];
            const bf16x8 ap1 = *(const bf16x8*)&Ps[wave][l15][32 + q4 * 8];
            #pragma unroll
            for (int d = 0; d < 8; ++d) {
                const bf16x8 bv0 = *(const bf16x8*)&Vt[d * 16 + l15][(q4 ^ vkey7) * 8];
                const bf16x8 bv1 = *(const bf16x8*)&Vt[d * 16 + l15][((4 + q4) ^ vkey7) * 8];
                oa[d] = __builtin_amdgcn_mfma_f32_16x16x32_bf16(ap0, bv0, oa[d], 0, 0, 0);
                oa[d] = __builtin_amdgcn_mfma_f32_16x16x32_bf16(ap1, bv1, oa[d], 0, 0, 0);
            }
        }

        // write partials (unnormalized o in bf16, running m,l)
        const int R0 = b * SEQ + tt * 64 + wave * 16 + q4 * 4;
        unsigned short* op = oPb + (size_t)h * NROWS * HD;
        #pragma unroll
        for (int d = 0; d < 8; ++d)
            #pragma unroll
            for (int r = 0; r < 4; ++r)
                op[(size_t)(R0 + r) * HD + d * 16 + l15] = f2bf_rne(oa[d][r]);
        if (l15 == 0) {
            #pragma unroll
            for (int r = 0; r < 4; ++r) {
                mP[h * NROWS + R0 + r] = m_r[r];
                lP[h * NROWS + R0 + r] = l_r[r];
            }
        }
    }
}

// ---------------------------------------------------------------------------
// merge the four kv-quarter partials; apply 1/l and OSCALE.
// ---------------------------------------------------------------------------
__global__ __launch_bounds__(256) void flash_merge(
    const unsigned short* __restrict__ oPb, const float* __restrict__ mP,
    const float* __restrict__ lP, float* __restrict__ out)
{
    const int idx = blockIdx.x * 256 + threadIdx.x;   // per float4
    const int r = idx >> 5, c = (idx & 31) * 4;
    float m[4], l[4];
    #pragma unroll
    for (int i = 0; i < 4; ++i) { m[i] = mP[i * NROWS + r]; l[i] = lP[i * NROWS + r]; }
    float M = fmaxf(fmaxf(m[0], m[1]), fmaxf(m[2], m[3]));
    float a[4], lsum = 0.f;
    #pragma unroll
    for (int i = 0; i < 4; ++i) { a[i] = __expf(m[i] - M); lsum += l[i] * a[i]; }
    const float inv = OSCALE / lsum;
    float ox = 0.f, oy = 0.f, oz = 0.f, ow = 0.f;
    #pragma unroll
    for (int i = 0; i < 4; ++i) {
        const ushort4 ov = *(const ushort4*)(oPb + (size_t)i * NROWS * HD + (size_t)r * HD + c);
        ox += a[i] * bf2f(ov.x); oy += a[i] * bf2f(ov.y);
        oz += a[i] * bf2f(ov.z); ow += a[i] * bf2f(ov.w);
    }
    float4 o; o.x = ox * inv; o.y = oy * inv; o.z = oz * inv; o.w = ow * inv;
    *(float4*)(out + (size_t)r * HD + c) = o;
}

// ---------------------------------------------------------------------------
extern "C" void kernel_launch(void* const* d_in, const int* in_sizes, int n_in,
                              void* d_out, int out_size, void* d_ws, size_t ws_size,
                              hipStream_t stream)
{
    (void)in_sizes; (void)n_in; (void)out_size; (void)ws_size;
    const float* x  = (const float*)d_in[0];
    const float* Wq = (const float*)d_in[1];
    const float* bq = (const float*)d_in[2];
    const float* Wk = (const float*)d_in[3];
    const float* bk = (const float*)d_in[4];
    const float* Wv = (const float*)d_in[5];
    const float* bv = (const float*)d_in[6];
    float* out = (float*)d_out;

    // workspace layout (bytes): ~41.4 MB total
    char* w = (char*)d_ws;
    unsigned short* qh  = (unsigned short*)(w);
    unsigned short* ql  = (unsigned short*)(w + 4194304);
    unsigned short* kh  = (unsigned short*)(w + 8388608);
    unsigned short* kl  = (unsigned short*)(w + 12582912);
    unsigned short* vth = (unsigned short*)(w + 16777216);
    unsigned short* wth = (unsigned short*)(w + 20971520);
    unsigned short* wtl = (unsigned short*)(w + 22544384);
    unsigned short* oPb = (unsigned short*)(w + 24117248);   // 4 x NROWS x HD bf16
    float* mP = (float*)(w + 40894464);                      // 4 x NROWS
    float* lP = (float*)(w + 41156608);                      // 4 x NROWS

    prep_w<<<dim3(32, 2, 3), 256, 0, stream>>>(Wq, Wk, Wv, wth, wtl);
    qkv_mfma<<<dim3(128, 3), 256, 0, stream>>>(x, bq, bk, bv, wth, wtl, qh, ql, kh, kl, vth);
    flash_mfma<<<512, 256, 0, stream>>>(qh, ql, kh, kl, vth, oPb, mP, lP);
    flash_merge<<<2048, 256, 0, stream>>>(oPb, mP, lP, out);
}